// Round 2
// baseline (11252.372 us; speedup 1.0000x reference)
//
#include <hip/hip_runtime.h>
#include <hip/hip_bf16.h>

#define NN 50000      // nodes
#define NE 100000     // edges
#define NG 2500       // graphs
#define DD 64         // dim
#define WW 128        // edge-mlp width

__device__ __forceinline__ float sigf(float x) { return 1.0f / (1.0f + __expf(-x)); }

__device__ __forceinline__ unsigned f2enc(float f) {
    unsigned b = __float_as_uint(f);
    return (b & 0x80000000u) ? ~b : (b | 0x80000000u);
}
__device__ __forceinline__ float enc2f(unsigned e) {
    unsigned b = (e & 0x80000000u) ? (e & 0x7fffffffu) : ~e;
    return __uint_as_float(b);
}
__device__ __forceinline__ unsigned short f2bf(float f) {
    unsigned u = __float_as_uint(f);
    unsigned r = (u + 0x7fffu + ((u >> 16) & 1u)) >> 16;
    return (unsigned short)r;
}
__device__ __forceinline__ float bf2f(unsigned short u) {
    return __uint_as_float(((unsigned)u) << 16);
}

// zero n4 float4's
__global__ void k_zero4(float4* __restrict__ p, int n4) {
    int i = blockIdx.x * 256 + threadIdx.x;
    if (i < n4) p[i] = make_float4(0.f, 0.f, 0.f, 0.f);
}

// dst[c*rows + r] = src[r*cols + c]
__global__ void k_transpose(float* dst, const float* src, int rows, int cols) {
    int idx = blockIdx.x * 256 + threadIdx.x;
    if (idx >= rows * cols) return;
    int r = idx / cols, c = idx % cols;
    dst[c * rows + r] = src[idx];
}

// s[n,o] = relu([x|z] @ lin0_w + b)
__global__ void k_lin0(const float* __restrict__ x, const float* __restrict__ z,
                       const float* __restrict__ w, const float* __restrict__ b,
                       float* __restrict__ s) {
    int idx = blockIdx.x * 256 + threadIdx.x;  // NN*64 exact
    int n = idx >> 6, o = idx & 63;
    float acc = b[o];
#pragma unroll
    for (int i = 0; i < 15; i++) acc += x[n * 15 + i] * w[i * 64 + o];
    acc += z[n] * w[15 * 64 + o];
    s[idx] = fmaxf(acc, 0.0f);
}

__global__ void k_deg(const int* __restrict__ dstI, float* __restrict__ deg) {
    int e = blockIdx.x * 256 + threadIdx.x;
    if (e < NE) atomicAdd(&deg[dstI[e]], 1.0f);
}

// hidden[e,j] = relu(edge_attr @ w1 + b1)
__global__ void k_emlp1(const float* __restrict__ ea, const float* __restrict__ w1,
                        const float* __restrict__ b1, float* __restrict__ hid) {
    int idx = blockIdx.x * 256 + threadIdx.x;  // NE*128 exact
    int e = idx >> 7, j = idx & 127;
    float acc = b1[j];
#pragma unroll
    for (int i = 0; i < 5; i++) acc += ea[e * 5 + i] * w1[i * 128 + j];
    hid[idx] = fmaxf(acc, 0.0f);
}

// ew[e_local, 4096] = hid[e_local,:] @ w2 + b2 ; tile: 32 edges x 256 cols / block(256)
// hid is pre-offset to the chunk base; ew indexed locally.
template <int BF>
__global__ void k_ew(const float* __restrict__ hid, const float* __restrict__ w2,
                     const float* __restrict__ b2, void* __restrict__ ew) {
    __shared__ float hlds[32][WW];  // 16 KB
    int t = threadIdx.x;
    int e0 = blockIdx.x * 32;
    int c0 = blockIdx.y * 256;
    for (int idx4 = t; idx4 < 32 * WW / 4; idx4 += 256) {
        int el = idx4 >> 5;          // 32 float4 per 128-row
        int h4 = (idx4 & 31) * 4;
        *(float4*)&hlds[el][h4] = *(const float4*)&hid[(size_t)(e0 + el) * WW + h4];
    }
    __syncthreads();
    int lane = t & 63;
    int eg = t >> 6;                 // 4 groups of 8 edges
    int col = c0 + lane * 4;
    float4 acc[8];
#pragma unroll
    for (int j = 0; j < 8; j++) acc[j] = make_float4(0, 0, 0, 0);
    for (int h = 0; h < WW; h++) {
        float4 w4 = *(const float4*)&w2[(size_t)h * 4096 + col];
#pragma unroll
        for (int j = 0; j < 8; j++) {
            float sv = hlds[eg * 8 + j][h];
            acc[j].x += sv * w4.x; acc[j].y += sv * w4.y;
            acc[j].z += sv * w4.z; acc[j].w += sv * w4.w;
        }
    }
    float4 bb = *(const float4*)&b2[col];
#pragma unroll
    for (int j = 0; j < 8; j++) {
        int e = e0 + eg * 8 + j;
        size_t off = (size_t)e * 4096 + col;
        float vx = acc[j].x + bb.x, vy = acc[j].y + bb.y;
        float vz = acc[j].z + bb.z, vw = acc[j].w + bb.w;
        if (BF) {
            ushort4 u;
            u.x = f2bf(vx); u.y = f2bf(vy); u.z = f2bf(vz); u.w = f2bf(vw);
            *(ushort4*)((unsigned short*)ew + off) = u;
        } else {
            *(float4*)((float*)ew + off) = make_float4(vx, vy, vz, vw);
        }
    }
}

// msg[e,:] = s[src[e],:] @ ew[e_local]; atomic-scatter into aggr[dst[e],:]
// srcI/dstI pre-offset to chunk base; ew indexed locally.
// block 256 = 16 edges x 16 lanes (float4 over output dim)
template <int BF>
__global__ void k_msg(const float* __restrict__ s, const void* __restrict__ ew,
                      const int* __restrict__ srcI, const int* __restrict__ dstI,
                      float* __restrict__ aggr) {
    __shared__ float slds[16][65];
    int t = threadIdx.x;
    int e0 = blockIdx.x * 16;
    for (int idx = t; idx < 16 * 64; idx += 256) {
        int el = idx >> 6, o = idx & 63;
        slds[el][o] = s[(size_t)srcI[e0 + el] * 64 + o];
    }
    __syncthreads();
    int el = t >> 4;
    int oc = (t & 15) * 4;
    int e = e0 + el;
    float ax = 0, ay = 0, az = 0, aw = 0;
    if (BF) {
        const unsigned short* p = (const unsigned short*)ew + (size_t)e * 4096 + oc;
        for (int i = 0; i < 64; i++) {
            ushort4 u = *(const ushort4*)(p + (size_t)i * 64);
            float si = slds[el][i];
            ax += si * bf2f(u.x); ay += si * bf2f(u.y);
            az += si * bf2f(u.z); aw += si * bf2f(u.w);
        }
    } else {
        const float* p = (const float*)ew + (size_t)e * 4096 + oc;
        for (int i = 0; i < 64; i++) {
            float4 w4 = *(const float4*)(p + (size_t)i * 64);
            float si = slds[el][i];
            ax += si * w4.x; ay += si * w4.y; az += si * w4.z; aw += si * w4.w;
        }
    }
    int d = dstI[e];
    atomicAdd(&aggr[(size_t)d * 64 + oc + 0], ax);
    atomicAdd(&aggr[(size_t)d * 64 + oc + 1], ay);
    atomicAdd(&aggr[(size_t)d * 64 + oc + 2], az);
    atomicAdd(&aggr[(size_t)d * 64 + oc + 3], aw);
}

// NNConv root+bias+relu, then GRU cell. One wave per node (s == out == h buffer).
__global__ void k_combine(float* __restrict__ s, const float* __restrict__ aggr,
                          const float* __restrict__ deg, const float* __restrict__ R,
                          const float* __restrict__ cb, const float* __restrict__ WiT,
                          const float* __restrict__ WhT, const float* __restrict__ bi,
                          const float* __restrict__ bh) {
    int idx = blockIdx.x * 256 + threadIdx.x;  // NN*64 exact
    int n = idx >> 6, o = idx & 63;
    float sv = s[idx];
    float acc = aggr[idx] / fmaxf(deg[n], 1.0f) + cb[o];
    for (int i = 0; i < 64; i++) acc += __shfl(sv, i, 64) * R[i * 64 + o];
    float m = fmaxf(acc, 0.0f);
    float gir = bi[o], giz = bi[64 + o], gin = bi[128 + o];
    float ghr = bh[o], ghz = bh[64 + o], ghn = bh[128 + o];
    for (int i = 0; i < 64; i++) {
        float mi = __shfl(m, i, 64);
        float hi = __shfl(sv, i, 64);
        gir += mi * WiT[i * 192 + o];
        giz += mi * WiT[i * 192 + 64 + o];
        gin += mi * WiT[i * 192 + 128 + o];
        ghr += hi * WhT[i * 192 + o];
        ghz += hi * WhT[i * 192 + 64 + o];
        ghn += hi * WhT[i * 192 + 128 + o];
    }
    float r = sigf(gir + ghr);
    float zg = sigf(giz + ghz);
    float ng = tanhf(gin + r * ghn);
    s[idx] = (1.0f - zg) * ng + zg * sv;
}

// LSTM cell, one block(256) per graph
__global__ void k_lstm(const float* __restrict__ q_star, float* __restrict__ hh,
                       float* __restrict__ cc, const float* __restrict__ LiT,
                       const float* __restrict__ LhT, const float* __restrict__ bi,
                       const float* __restrict__ bh) {
    __shared__ float qs[128], hv[64], g[256];
    int b = blockIdx.x, t = threadIdx.x;
    if (t < 128) qs[t] = q_star[b * 128 + t];
    else if (t < 192) hv[t - 128] = hh[b * 64 + t - 128];
    __syncthreads();
    float acc = bi[t] + bh[t];
    for (int k = 0; k < 128; k++) acc += qs[k] * LiT[k * 256 + t];
    for (int k = 0; k < 64; k++) acc += hv[k] * LhT[k * 256 + t];
    g[t] = acc;
    __syncthreads();
    if (t < 64) {
        float c_new = sigf(g[64 + t]) * cc[b * 64 + t] + sigf(g[t]) * tanhf(g[128 + t]);
        cc[b * 64 + t] = c_new;
        hh[b * 64 + t] = sigf(g[192 + t]) * tanhf(c_new);
    }
}

// e[n] = dot(out[n], q[batch[n]]) and segment-max via order-preserving uint atomicMax
__global__ void k_dot(const float* __restrict__ s, const float* __restrict__ hh,
                      const int* __restrict__ batch, float* __restrict__ e_v,
                      unsigned* __restrict__ emax) {
    int n = blockIdx.x * 256 + threadIdx.x;
    if (n >= NN) return;
    int b = batch[n];
    const float4* sp = (const float4*)&s[(size_t)n * 64];
    const float4* qp = (const float4*)&hh[(size_t)b * 64];
    float acc = 0;
#pragma unroll
    for (int i = 0; i < 16; i++) {
        float4 a = sp[i], q = qp[i];
        acc += a.x * q.x + a.y * q.y + a.z * q.z + a.w * q.w;
    }
    e_v[n] = acc;
    atomicMax(&emax[b], f2enc(acc));
}

// a = exp(e - emax); asum += a; r_pool += a*out  (normalized later)
__global__ void k_attn(const float* __restrict__ s, const float* __restrict__ e_v,
                       const unsigned* __restrict__ emax, const int* __restrict__ batch,
                       float* __restrict__ asum, float* __restrict__ r_pool) {
    int idx = blockIdx.x * 256 + threadIdx.x;  // NN*64 exact
    int n = idx >> 6, o = idx & 63;
    int b = batch[n];
    float a = __expf(e_v[n] - enc2f(emax[b]));
    atomicAdd(&r_pool[(size_t)b * 64 + o], a * s[idx]);
    if (o == 0) atomicAdd(&asum[b], a);
}

__global__ void k_qstar(float* __restrict__ q_star, const float* __restrict__ hh,
                        const float* __restrict__ r_pool, const float* __restrict__ asum) {
    int idx = blockIdx.x * 256 + threadIdx.x;  // NG*128 exact
    int b = idx >> 7, j = idx & 127;
    q_star[idx] = (j < 64) ? hh[b * 64 + j]
                           : r_pool[b * 64 + j - 64] / (asum[b] + 1e-16f);
}

// y[b] = relu(q_star @ lin1 + b1) @ lin2 + b2 ; one wave per graph
__global__ void k_final(const float* __restrict__ q_star, const float* __restrict__ w1,
                        const float* __restrict__ b1, const float* __restrict__ w2,
                        const float* __restrict__ b2, float* __restrict__ y) {
    __shared__ float qs[128];
    int b = blockIdx.x, t = threadIdx.x;  // 64 threads
    qs[t] = q_star[b * 128 + t];
    qs[64 + t] = q_star[b * 128 + 64 + t];
    __syncthreads();
    float acc = b1[t];
    for (int k = 0; k < 128; k++) acc += qs[k] * w1[k * 64 + t];
    float hid = fmaxf(acc, 0.0f) * w2[t];
#pragma unroll
    for (int off = 32; off; off >>= 1) hid += __shfl_down(hid, off, 64);
    if (t == 0) y[b] = hid + b2[0];
}

static inline void zero_f(float* p, size_t nfloats, hipStream_t stream) {
    int n4 = (int)(nfloats / 4);
    k_zero4<<<(n4 + 255) / 256, 256, 0, stream>>>((float4*)p, n4);
}

extern "C" void kernel_launch(void* const* d_in, const int* in_sizes, int n_in,
                              void* d_out, int out_size, void* d_ws, size_t ws_size,
                              hipStream_t stream) {
    const float* x       = (const float*)d_in[0];
    const float* z       = (const float*)d_in[1];
    const float* ea      = (const float*)d_in[2];
    const float* lin0_w  = (const float*)d_in[3];
    const float* lin0_b  = (const float*)d_in[4];
    const float* emlp_w1 = (const float*)d_in[5];
    const float* emlp_b1 = (const float*)d_in[6];
    const float* emlp_w2 = (const float*)d_in[7];
    const float* emlp_b2 = (const float*)d_in[8];
    const float* conv_r  = (const float*)d_in[9];
    const float* conv_b  = (const float*)d_in[10];
    const float* gru_wi  = (const float*)d_in[11];
    const float* gru_wh  = (const float*)d_in[12];
    const float* gru_bi  = (const float*)d_in[13];
    const float* gru_bh  = (const float*)d_in[14];
    const float* lstm_wi = (const float*)d_in[15];
    const float* lstm_wh = (const float*)d_in[16];
    const float* lstm_bi = (const float*)d_in[17];
    const float* lstm_bh = (const float*)d_in[18];
    const float* lin1_w  = (const float*)d_in[19];
    const float* lin1_b  = (const float*)d_in[20];
    const float* lin2_w  = (const float*)d_in[21];
    const float* lin2_b  = (const float*)d_in[22];
    const int* eidx      = (const int*)d_in[23];
    const int* batch     = (const int*)d_in[24];
    const int* srcI = eidx;
    const int* dstI = eidx + NE;
    float* y = (float*)d_out;

    char* w = (char*)d_ws;
    size_t off = 0;
    auto alloc = [&](size_t bytes) -> void* {
        void* p = w + off;
        off += (bytes + 255) & ~(size_t)255;
        return p;
    };
    float* s      = (float*)alloc((size_t)NN * 64 * 4);
    float* aggr   = (float*)alloc((size_t)NN * 64 * 4);
    float* hid    = (float*)alloc((size_t)NE * WW * 4);
    float* deg    = (float*)alloc((size_t)NN * 4);       // 50000 -> pad 200192 B
    float* e_v    = (float*)alloc((size_t)NN * 4);
    // next three contiguous (with 256B pads) -> zeroed as one region
    unsigned* emax= (unsigned*)alloc((size_t)NG * 4);    // 10240 B padded
    float* asum   = (float*)alloc((size_t)NG * 4);       // 10240 B padded
    float* r_pool = (float*)alloc((size_t)NG * 64 * 4);  // 640000 B exact
    // next three contiguous, no padding (all multiples of 256)
    float* q_star = (float*)alloc((size_t)NG * 128 * 4); // 1280000 B
    float* hh     = (float*)alloc((size_t)NG * 64 * 4);  // 640000 B
    float* cc     = (float*)alloc((size_t)NG * 64 * 4);  // 640000 B
    float* WiT    = (float*)alloc(192 * 64 * 4);
    float* WhT    = (float*)alloc(192 * 64 * 4);
    float* LiT    = (float*)alloc(256 * 128 * 4);
    float* LhT    = (float*)alloc(256 * 64 * 4);
    void* ew = (void*)(w + off);
    size_t leftover = (ws_size > off) ? (ws_size - off) : 0;

    // Tier select (pure function of ws_size -> identical every call, graph-safe):
    //   A: full f32 ew (1638.4 MB), materialize once
    //   B: full bf16 ew (819.2 MB), materialize once
    //   C: f32 chunk, recomputed per step. Chunk sizes divide NE, mult of 32.
    int CE = 0, ew_bf = 0;
    if (leftover >= (size_t)NE * 4096 * 4)      { CE = NE; ew_bf = 0; }
    else if (leftover >= (size_t)NE * 4096 * 2) { CE = NE; ew_bf = 1; }
    else {
        const int ladder[4] = {20000, 4000, 800, 160};
        for (int i = 0; i < 4; i++)
            if ((size_t)ladder[i] * 4096 * 4 <= leftover) { CE = ladder[i]; break; }
        if (CE == 0) CE = 160;  // below ~83 MB total ws nothing is salvageable anyway
    }

    // weight transposes (cheap; ws re-poisoned each call so redo every launch)
    k_transpose<<<(192 * 64 + 255) / 256, 256, 0, stream>>>(WiT, gru_wi, 192, 64);
    k_transpose<<<(192 * 64 + 255) / 256, 256, 0, stream>>>(WhT, gru_wh, 192, 64);
    k_transpose<<<(256 * 128 + 255) / 256, 256, 0, stream>>>(LiT, lstm_wi, 256, 128);
    k_transpose<<<(256 * 64 + 255) / 256, 256, 0, stream>>>(LhT, lstm_wh, 256, 64);

    // node embedding, degree, edge MLP layer 1
    k_lin0<<<NN * 64 / 256, 256, 0, stream>>>(x, z, lin0_w, lin0_b, s);
    zero_f(deg, NN, stream);
    k_deg<<<(NE + 255) / 256, 256, 0, stream>>>(dstI, deg);
    k_emlp1<<<NE * WW / 256, 256, 0, stream>>>(ea, emlp_w1, emlp_b1, hid);

    if (CE == NE) {  // tiers A/B: materialize ew once
        dim3 ewg(NE / 32, 4096 / 256);
        if (ew_bf) k_ew<1><<<ewg, 256, 0, stream>>>(hid, emlp_w2, emlp_b2, ew);
        else       k_ew<0><<<ewg, 256, 0, stream>>>(hid, emlp_w2, emlp_b2, ew);
    }

    // 5 message-passing + GRU steps
    for (int step = 0; step < 5; step++) {
        zero_f(aggr, (size_t)NN * 64, stream);
        if (CE == NE) {
            if (ew_bf) k_msg<1><<<NE / 16, 256, 0, stream>>>(s, ew, srcI, dstI, aggr);
            else       k_msg<0><<<NE / 16, 256, 0, stream>>>(s, ew, srcI, dstI, aggr);
        } else {     // tier C: recompute ew chunk-by-chunk each step
            dim3 ewg(CE / 32, 4096 / 256);
            for (int c = 0; c < NE; c += CE) {
                k_ew<0><<<ewg, 256, 0, stream>>>(hid + (size_t)c * WW,
                                                 emlp_w2, emlp_b2, ew);
                k_msg<0><<<CE / 16, 256, 0, stream>>>(s, ew, srcI + c, dstI + c, aggr);
            }
        }
        k_combine<<<NN * 64 / 256, 256, 0, stream>>>(s, aggr, deg, conv_r, conv_b,
                                                     WiT, WhT, gru_bi, gru_bh);
    }

    // Set2Set
    zero_f(q_star, (size_t)NG * 128 + NG * 64 + NG * 64, stream);  // q_star|hh|cc
    for (int it = 0; it < 5; it++) {
        k_lstm<<<NG, 256, 0, stream>>>(q_star, hh, cc, LiT, LhT, lstm_bi, lstm_bh);
        // emax(10240B pad) | asum(10240B pad) | r_pool(640000B) zeroed as one region
        zero_f((float*)emax, (10240 + 10240 + 640000) / 4, stream);
        k_dot<<<(NN + 255) / 256, 256, 0, stream>>>(s, hh, batch, e_v, emax);
        k_attn<<<NN * 64 / 256, 256, 0, stream>>>(s, e_v, emax, batch, asum, r_pool);
        k_qstar<<<NG * 128 / 256, 256, 0, stream>>>(q_star, hh, r_pool, asum);
    }
    k_final<<<NG, 64, 0, stream>>>(q_star, lin1_w, lin1_b, lin2_w, lin2_b, y);
}

// Round 3
// 1973.602 us; speedup vs baseline: 5.7014x; 5.7014x over previous
//
#include <hip/hip_runtime.h>
#include <hip/hip_bf16.h>

#define NN 50000      // nodes
#define NE 100000     // edges
#define NG 2500       // graphs
#define WW 128        // edge-mlp width
#define EPAD 100096   // 782 blocks * 128 edges
#define KCH 264       // K chunks of 32: 8448 = 132 h-rows * 64 (128 hid + 1 bias + 3 zero)

typedef _Float16 h8 __attribute__((ext_vector_type(8)));
typedef _Float16 h4 __attribute__((ext_vector_type(4)));
typedef float    f4 __attribute__((ext_vector_type(4)));

__device__ __forceinline__ float sigf(float x) { return 1.0f / (1.0f + __expf(-x)); }

__device__ __forceinline__ unsigned f2enc(float f) {
    unsigned b = __float_as_uint(f);
    return (b & 0x80000000u) ? ~b : (b | 0x80000000u);
}
__device__ __forceinline__ float enc2f(unsigned e) {
    unsigned b = (e & 0x80000000u) ? (e & 0x7fffffffu) : ~e;
    return __uint_as_float(b);
}

// zero n4 float4's
__global__ void k_zero4(float4* __restrict__ p, int n4) {
    int i = blockIdx.x * 256 + threadIdx.x;
    if (i < n4) p[i] = make_float4(0.f, 0.f, 0.f, 0.f);
}

// dst[c*rows + r] = src[r*cols + c]
__global__ void k_transpose(float* dst, const float* src, int rows, int cols) {
    int idx = blockIdx.x * 256 + threadIdx.x;
    if (idx >= rows * cols) return;
    int r = idx / cols, c = idx % cols;
    dst[c * rows + r] = src[idx];
}

// s[n,o] = relu([x|z] @ lin0_w + b)
__global__ void k_lin0(const float* __restrict__ x, const float* __restrict__ z,
                       const float* __restrict__ w, const float* __restrict__ b,
                       float* __restrict__ s) {
    int idx = blockIdx.x * 256 + threadIdx.x;  // NN*64 exact
    int n = idx >> 6, o = idx & 63;
    float acc = b[o];
#pragma unroll
    for (int i = 0; i < 15; i++) acc += x[n * 15 + i] * w[i * 64 + o];
    acc += z[n] * w[15 * 64 + o];
    s[idx] = fmaxf(acc, 0.0f);
}

__global__ void k_deg(const int* __restrict__ dstI, float* __restrict__ deg) {
    int e = blockIdx.x * 256 + threadIdx.x;
    if (e < NE) atomicAdd(&deg[dstI[e]], 1.0f);
}

// s -> f16 copy (4 elements/thread)
__global__ void k_s16(const float* __restrict__ s, _Float16* __restrict__ s16) {
    int i = blockIdx.x * 256 + threadIdx.x;  // NN*16 exact
    float4 v = ((const float4*)s)[i];
    h4 o = { (_Float16)v.x, (_Float16)v.y, (_Float16)v.z, (_Float16)v.w };
    *((h4*)s16 + i) = o;
}

// edge MLP layer 1 fused with transpose to f16: hidT[h][e], h=0..131
// rows 0..127: relu(ea@w1+b1); row 128: 1.0 (bias row); rows 129..131: 0
__global__ void k_emlp_t(const float* __restrict__ ea, const float* __restrict__ w1,
                         const float* __restrict__ b1, _Float16* __restrict__ hidT) {
    __shared__ _Float16 hl[132][64];
    int t = threadIdx.x;
    int e0 = blockIdx.x * 64;             // 1564 blocks
    int e_l = t & 63, w = t >> 6;
    int e = e0 + e_l;
    float a0 = 0, a1 = 0, a2 = 0, a3 = 0, a4 = 0;
    if (e < NE) {
        a0 = ea[e * 5 + 0]; a1 = ea[e * 5 + 1]; a2 = ea[e * 5 + 2];
        a3 = ea[e * 5 + 3]; a4 = ea[e * 5 + 4];
    }
    for (int h = w * 32; h < w * 32 + 32; h++) {   // h uniform per wave -> scalar w1/b1
        float acc = b1[h];
        acc += a0 * w1[0 * 128 + h] + a1 * w1[1 * 128 + h] + a2 * w1[2 * 128 + h]
             + a3 * w1[3 * 128 + h] + a4 * w1[4 * 128 + h];
        hl[h][e_l] = (_Float16)fmaxf(acc, 0.0f);
    }
    if (t < 64) hl[128][t] = (_Float16)1.0f;
    else if (t < 128) hl[129][t - 64] = (_Float16)0.0f;
    else if (t < 192) hl[130][t - 128] = (_Float16)0.0f;
    else hl[131][t - 192] = (_Float16)0.0f;
    __syncthreads();
#pragma unroll
    for (int it = 0; it < 33; it++) {     // 132*64 = 8448 = 33*256
        int idx = it * 256 + t;
        int h = idx >> 6, el = idx & 63;
        hidT[(size_t)h * EPAD + e0 + el] = hl[h][el];
    }
}

// Pre-arrange B = [w2 ; b2 ; 0] (shape [8448,64]) into MFMA-fragment order:
// Bp unit g=((c*4+tt)*64+l) holds 8 f16: B[c*32 + (l>>4)*8 + j][tt*16 + (l&15)]
__global__ void k_prep_B(const float* __restrict__ w2, const float* __restrict__ b2,
                         _Float16* __restrict__ Bp) {
    int g = blockIdx.x * 256 + threadIdx.x;   // KCH*4*64 = 67584 exact
    int l = g & 63, tt = (g >> 6) & 3, c = g >> 8;
    int n = tt * 16 + (l & 15);
    int kb = c * 32 + (l >> 4) * 8;
    h8 v;
#pragma unroll
    for (int j = 0; j < 8; j++) {
        int k = kb + j;
        float f = 0.0f;
        if (k < 8192) f = w2[(size_t)k * 64 + n];
        else if (k < 8256) f = b2[(k - 8192) * 64 + n];
        v[j] = (_Float16)f;
    }
    *((h8*)Bp + g) = v;
}

// Fused NNConv message: msg[e,:] = (hid[e]⊗s[src[e]]) @ B, atomic-scatter to aggr[dst[e]]
// block = 256 thr = 4 waves; wave: 32 edges x 64 cols; block: 128 edges. 782 blocks.
__global__ __launch_bounds__(256) void k_fused(
        const _Float16* __restrict__ s16, const _Float16* __restrict__ hidT,
        const _Float16* __restrict__ Bp, const int* __restrict__ srcI,
        const int* __restrict__ dstI, float* __restrict__ aggr) {
    __shared__ uint4 Bl[2048];            // 8 chunks * 4 tiles * 64 lanes * 16B = 32 KB
    __shared__ _Float16 hl[4][128];       // 4 h-rows * 128 edges
    int t = threadIdx.x, w = t >> 6, lane = t & 63;
    int m = lane & 15, q = lane >> 4;
    int e_blk = blockIdx.x * 128;
    int ew0 = e_blk + w * 32;

    // per-lane s fragments (reused across whole K loop)
    h8 slo[2], shi[2];
#pragma unroll
    for (int mt = 0; mt < 2; mt++) {
        int e = ew0 + mt * 16 + m;
        int src = (e < NE) ? srcI[e] : 0;
        const _Float16* sp = s16 + (size_t)src * 64;
        slo[mt] = *(const h8*)(sp + q * 8);
        shi[mt] = *(const h8*)(sp + 32 + q * 8);
    }
    f4 acc[2][4];
#pragma unroll
    for (int mt = 0; mt < 2; mt++)
#pragma unroll
        for (int nt = 0; nt < 4; nt++) acc[mt][nt] = (f4){0.f, 0.f, 0.f, 0.f};

    for (int sc = 0; sc < 33; sc++) {     // 33 super-chunks * 8 chunks = 264
        __syncthreads();
        const uint4* bsrc = (const uint4*)Bp + (size_t)sc * 2048;
#pragma unroll
        for (int r = 0; r < 8; r++) Bl[r * 256 + t] = bsrc[r * 256 + t];
        {   // stage hid rows sc*4 .. sc*4+3 for this block's 128 edges
            int h_l = t >> 6, e2 = (t & 63) * 2;
            unsigned v = *(const unsigned*)(hidT + (size_t)(sc * 4 + h_l) * EPAD + e_blk + e2);
            *((unsigned*)&hl[h_l][0] + (t & 63)) = v;
        }
        __syncthreads();
#pragma unroll
        for (int cc = 0; cc < 8; cc++) {
            h8 b0 = *(const h8*)&Bl[(cc * 4 + 0) * 64 + lane];
            h8 b1 = *(const h8*)&Bl[(cc * 4 + 1) * 64 + lane];
            h8 b2 = *(const h8*)&Bl[(cc * 4 + 2) * 64 + lane];
            h8 b3 = *(const h8*)&Bl[(cc * 4 + 3) * 64 + lane];
            int hli = cc >> 1;
#pragma unroll
            for (int mt = 0; mt < 2; mt++) {
                _Float16 hv = hl[hli][w * 32 + mt * 16 + m];
                h8 a = ((cc & 1) ? shi[mt] : slo[mt]) * hv;
                acc[mt][0] = __builtin_amdgcn_mfma_f32_16x16x32_f16(a, b0, acc[mt][0], 0, 0, 0);
                acc[mt][1] = __builtin_amdgcn_mfma_f32_16x16x32_f16(a, b1, acc[mt][1], 0, 0, 0);
                acc[mt][2] = __builtin_amdgcn_mfma_f32_16x16x32_f16(a, b2, acc[mt][2], 0, 0, 0);
                acc[mt][3] = __builtin_amdgcn_mfma_f32_16x16x32_f16(a, b3, acc[mt][3], 0, 0, 0);
            }
        }
    }
    // epilogue: C/D layout col=lane&15, row=q*4+reg -> edge = base + q*4 + r
#pragma unroll
    for (int mt = 0; mt < 2; mt++) {
        int eb = ew0 + mt * 16 + q * 4;
#pragma unroll
        for (int r = 0; r < 4; r++) {
            int e = eb + r;
            if (e < NE) {
                int d = dstI[e];
                float* ap = aggr + (size_t)d * 64 + m;
                atomicAdd(ap + 0,  acc[mt][0][r]);
                atomicAdd(ap + 16, acc[mt][1][r]);
                atomicAdd(ap + 32, acc[mt][2][r]);
                atomicAdd(ap + 48, acc[mt][3][r]);
            }
        }
    }
}

// NNConv root+bias+relu, then GRU cell. One wave per node (s == out == h buffer).
__global__ void k_combine(float* __restrict__ s, const float* __restrict__ aggr,
                          const float* __restrict__ deg, const float* __restrict__ R,
                          const float* __restrict__ cb, const float* __restrict__ WiT,
                          const float* __restrict__ WhT, const float* __restrict__ bi,
                          const float* __restrict__ bh) {
    int idx = blockIdx.x * 256 + threadIdx.x;  // NN*64 exact
    int n = idx >> 6, o = idx & 63;
    float sv = s[idx];
    float acc = aggr[idx] / fmaxf(deg[n], 1.0f) + cb[o];
    for (int i = 0; i < 64; i++) acc += __shfl(sv, i, 64) * R[i * 64 + o];
    float m = fmaxf(acc, 0.0f);
    float gir = bi[o], giz = bi[64 + o], gin = bi[128 + o];
    float ghr = bh[o], ghz = bh[64 + o], ghn = bh[128 + o];
    for (int i = 0; i < 64; i++) {
        float mi = __shfl(m, i, 64);
        float hi = __shfl(sv, i, 64);
        gir += mi * WiT[i * 192 + o];
        giz += mi * WiT[i * 192 + 64 + o];
        gin += mi * WiT[i * 192 + 128 + o];
        ghr += hi * WhT[i * 192 + o];
        ghz += hi * WhT[i * 192 + 64 + o];
        ghn += hi * WhT[i * 192 + 128 + o];
    }
    float r = sigf(gir + ghr);
    float zg = sigf(giz + ghz);
    float ng = tanhf(gin + r * ghn);
    s[idx] = (1.0f - zg) * ng + zg * sv;
}

// LSTM cell, one block(256) per graph
__global__ void k_lstm(const float* __restrict__ q_star, float* __restrict__ hh,
                       float* __restrict__ cc, const float* __restrict__ LiT,
                       const float* __restrict__ LhT, const float* __restrict__ bi,
                       const float* __restrict__ bh) {
    __shared__ float qs[128], hv[64], g[256];
    int b = blockIdx.x, t = threadIdx.x;
    if (t < 128) qs[t] = q_star[b * 128 + t];
    else if (t < 192) hv[t - 128] = hh[b * 64 + t - 128];
    __syncthreads();
    float acc = bi[t] + bh[t];
    for (int k = 0; k < 128; k++) acc += qs[k] * LiT[k * 256 + t];
    for (int k = 0; k < 64; k++) acc += hv[k] * LhT[k * 256 + t];
    g[t] = acc;
    __syncthreads();
    if (t < 64) {
        float c_new = sigf(g[64 + t]) * cc[b * 64 + t] + sigf(g[t]) * tanhf(g[128 + t]);
        cc[b * 64 + t] = c_new;
        hh[b * 64 + t] = sigf(g[192 + t]) * tanhf(c_new);
    }
}

// e[n] = dot(out[n], q[batch[n]]); segment-max via order-preserving uint atomicMax
__global__ void k_dot(const float* __restrict__ s, const float* __restrict__ hh,
                      const int* __restrict__ batch, float* __restrict__ e_v,
                      unsigned* __restrict__ emax) {
    int n = blockIdx.x * 256 + threadIdx.x;
    if (n >= NN) return;
    int b = batch[n];
    const float4* sp = (const float4*)&s[(size_t)n * 64];
    const float4* qp = (const float4*)&hh[(size_t)b * 64];
    float acc = 0;
#pragma unroll
    for (int i = 0; i < 16; i++) {
        float4 a = sp[i], q = qp[i];
        acc += a.x * q.x + a.y * q.y + a.z * q.z + a.w * q.w;
    }
    e_v[n] = acc;
    atomicMax(&emax[b], f2enc(acc));
}

// a = exp(e - emax); asum += a; r_pool += a*out
__global__ void k_attn(const float* __restrict__ s, const float* __restrict__ e_v,
                       const unsigned* __restrict__ emax, const int* __restrict__ batch,
                       float* __restrict__ asum, float* __restrict__ r_pool) {
    int idx = blockIdx.x * 256 + threadIdx.x;  // NN*64 exact
    int n = idx >> 6, o = idx & 63;
    int b = batch[n];
    float a = __expf(e_v[n] - enc2f(emax[b]));
    atomicAdd(&r_pool[(size_t)b * 64 + o], a * s[idx]);
    if (o == 0) atomicAdd(&asum[b], a);
}

__global__ void k_qstar(float* __restrict__ q_star, const float* __restrict__ hh,
                        const float* __restrict__ r_pool, const float* __restrict__ asum) {
    int idx = blockIdx.x * 256 + threadIdx.x;  // NG*128 exact
    int b = idx >> 7, j = idx & 127;
    q_star[idx] = (j < 64) ? hh[b * 64 + j]
                           : r_pool[b * 64 + j - 64] / (asum[b] + 1e-16f);
}

// y[b] = relu(q_star @ lin1 + b1) @ lin2 + b2 ; one wave per graph
__global__ void k_final(const float* __restrict__ q_star, const float* __restrict__ w1,
                        const float* __restrict__ b1, const float* __restrict__ w2,
                        const float* __restrict__ b2, float* __restrict__ y) {
    __shared__ float qs[128];
    int b = blockIdx.x, t = threadIdx.x;  // 64 threads
    qs[t] = q_star[b * 128 + t];
    qs[64 + t] = q_star[b * 128 + 64 + t];
    __syncthreads();
    float acc = b1[t];
    for (int k = 0; k < 128; k++) acc += qs[k] * w1[k * 64 + t];
    float hid = fmaxf(acc, 0.0f) * w2[t];
#pragma unroll
    for (int off = 32; off; off >>= 1) hid += __shfl_down(hid, off, 64);
    if (t == 0) y[b] = hid + b2[0];
}

static inline void zero_f(float* p, size_t nfloats, hipStream_t stream) {
    int n4 = (int)(nfloats / 4);
    k_zero4<<<(n4 + 255) / 256, 256, 0, stream>>>((float4*)p, n4);
}

extern "C" void kernel_launch(void* const* d_in, const int* in_sizes, int n_in,
                              void* d_out, int out_size, void* d_ws, size_t ws_size,
                              hipStream_t stream) {
    const float* x       = (const float*)d_in[0];
    const float* z       = (const float*)d_in[1];
    const float* ea      = (const float*)d_in[2];
    const float* lin0_w  = (const float*)d_in[3];
    const float* lin0_b  = (const float*)d_in[4];
    const float* emlp_w1 = (const float*)d_in[5];
    const float* emlp_b1 = (const float*)d_in[6];
    const float* emlp_w2 = (const float*)d_in[7];
    const float* emlp_b2 = (const float*)d_in[8];
    const float* conv_r  = (const float*)d_in[9];
    const float* conv_b  = (const float*)d_in[10];
    const float* gru_wi  = (const float*)d_in[11];
    const float* gru_wh  = (const float*)d_in[12];
    const float* gru_bi  = (const float*)d_in[13];
    const float* gru_bh  = (const float*)d_in[14];
    const float* lstm_wi = (const float*)d_in[15];
    const float* lstm_wh = (const float*)d_in[16];
    const float* lstm_bi = (const float*)d_in[17];
    const float* lstm_bh = (const float*)d_in[18];
    const float* lin1_w  = (const float*)d_in[19];
    const float* lin1_b  = (const float*)d_in[20];
    const float* lin2_w  = (const float*)d_in[21];
    const float* lin2_b  = (const float*)d_in[22];
    const int* eidx      = (const int*)d_in[23];
    const int* batch     = (const int*)d_in[24];
    const int* srcI = eidx;
    const int* dstI = eidx + NE;
    float* y = (float*)d_out;

    char* w = (char*)d_ws;
    size_t off = 0;
    auto alloc = [&](size_t bytes) -> void* {
        void* p = w + off;
        off += (bytes + 255) & ~(size_t)255;
        return p;
    };
    float* s      = (float*)alloc((size_t)NN * 64 * 4);
    float* aggr   = (float*)alloc((size_t)NN * 64 * 4);
    float* deg    = (float*)alloc((size_t)NN * 4);
    float* e_v    = (float*)alloc((size_t)NN * 4);
    // contiguous zero region: emax(10240B pad) | asum(10240B pad) | r_pool(640000B)
    unsigned* emax= (unsigned*)alloc((size_t)NG * 4);
    float* asum   = (float*)alloc((size_t)NG * 4);
    float* r_pool = (float*)alloc((size_t)NG * 64 * 4);
    // contiguous zero region: q_star | hh | cc (all 256-multiples)
    float* q_star = (float*)alloc((size_t)NG * 128 * 4);
    float* hh     = (float*)alloc((size_t)NG * 64 * 4);
    float* cc     = (float*)alloc((size_t)NG * 64 * 4);
    float* WiT    = (float*)alloc(192 * 64 * 4);
    float* WhT    = (float*)alloc(192 * 64 * 4);
    float* LiT    = (float*)alloc(256 * 128 * 4);
    float* LhT    = (float*)alloc(256 * 64 * 4);
    _Float16* s16 = (_Float16*)alloc((size_t)NN * 64 * 2);
    _Float16* hidT= (_Float16*)alloc((size_t)132 * EPAD * 2);
    _Float16* Bp  = (_Float16*)alloc((size_t)KCH * 4 * 64 * 8 * 2);
    (void)ws_size;  // total ~64 MB, well under proven capacity

    // weight transposes
    k_transpose<<<(192 * 64 + 255) / 256, 256, 0, stream>>>(WiT, gru_wi, 192, 64);
    k_transpose<<<(192 * 64 + 255) / 256, 256, 0, stream>>>(WhT, gru_wh, 192, 64);
    k_transpose<<<(256 * 128 + 255) / 256, 256, 0, stream>>>(LiT, lstm_wi, 256, 128);
    k_transpose<<<(256 * 64 + 255) / 256, 256, 0, stream>>>(LhT, lstm_wh, 256, 64);

    // node embedding, degree, edge-MLP layer 1 (-> hidT f16), B prep
    k_lin0<<<NN * 64 / 256, 256, 0, stream>>>(x, z, lin0_w, lin0_b, s);
    zero_f(deg, NN, stream);
    k_deg<<<(NE + 255) / 256, 256, 0, stream>>>(dstI, deg);
    k_emlp_t<<<EPAD / 64, 256, 0, stream>>>(ea, emlp_w1, emlp_b1, hidT);
    k_prep_B<<<KCH * 4 * 64 / 256, 256, 0, stream>>>(emlp_w2, emlp_b2, Bp);

    // 5 message-passing + GRU steps
    for (int step = 0; step < 5; step++) {
        zero_f(aggr, (size_t)NN * 64, stream);
        k_s16<<<NN * 16 / 256, 256, 0, stream>>>(s, s16);
        k_fused<<<EPAD / 128, 256, 0, stream>>>(s16, hidT, Bp, srcI, dstI, aggr);
        k_combine<<<NN * 64 / 256, 256, 0, stream>>>(s, aggr, deg, conv_r, conv_b,
                                                     WiT, WhT, gru_bi, gru_bh);
    }

    // Set2Set
    zero_f(q_star, (size_t)NG * 128 + NG * 64 + NG * 64, stream);
    for (int it = 0; it < 5; it++) {
        k_lstm<<<NG, 256, 0, stream>>>(q_star, hh, cc, LiT, LhT, lstm_bi, lstm_bh);
        zero_f((float*)emax, (10240 + 10240 + 640000) / 4, stream);
        k_dot<<<(NN + 255) / 256, 256, 0, stream>>>(s, hh, batch, e_v, emax);
        k_attn<<<NN * 64 / 256, 256, 0, stream>>>(s, e_v, emax, batch, asum, r_pool);
        k_qstar<<<NG * 128 / 256, 256, 0, stream>>>(q_star, hh, r_pool, asum);
    }
    k_final<<<NG, 64, 0, stream>>>(q_star, lin1_w, lin1_b, lin2_w, lin2_b, y);
}

// Round 4
// 1292.530 us; speedup vs baseline: 8.7057x; 1.5269x over previous
//
#include <hip/hip_runtime.h>
#include <hip/hip_bf16.h>

#define NN 50000      // nodes
#define NE 100000     // edges
#define NG 2500       // graphs
#define WW 128        // edge-mlp width
#define EPAD 100096   // 782 blocks * 128 edges
#define KCH 264       // K chunks of 32: 8448 = 132 h-rows * 64 (128 hid + 1 bias + 3 zero)

typedef _Float16 h8 __attribute__((ext_vector_type(8)));
typedef _Float16 h4 __attribute__((ext_vector_type(4)));
typedef float    f4 __attribute__((ext_vector_type(4)));

__device__ __forceinline__ float sigf(float x) { return 1.0f / (1.0f + __expf(-x)); }

__device__ __forceinline__ unsigned f2enc(float f) {
    unsigned b = __float_as_uint(f);
    return (b & 0x80000000u) ? ~b : (b | 0x80000000u);
}
__device__ __forceinline__ float enc2f(unsigned e) {
    unsigned b = (e & 0x80000000u) ? (e & 0x7fffffffu) : ~e;
    return __uint_as_float(b);
}

// zero n4 float4's
__global__ void k_zero4(float4* __restrict__ p, int n4) {
    int i = blockIdx.x * 256 + threadIdx.x;
    if (i < n4) p[i] = make_float4(0.f, 0.f, 0.f, 0.f);
}

// dst[c*rows + r] = src[r*cols + c]
__global__ void k_transpose(float* dst, const float* src, int rows, int cols) {
    int idx = blockIdx.x * 256 + threadIdx.x;
    if (idx >= rows * cols) return;
    int r = idx / cols, c = idx % cols;
    dst[c * rows + r] = src[idx];
}

// s[n,o] = relu([x|z] @ lin0_w + b)
__global__ void k_lin0(const float* __restrict__ x, const float* __restrict__ z,
                       const float* __restrict__ w, const float* __restrict__ b,
                       float* __restrict__ s) {
    int idx = blockIdx.x * 256 + threadIdx.x;  // NN*64 exact
    int n = idx >> 6, o = idx & 63;
    float acc = b[o];
#pragma unroll
    for (int i = 0; i < 15; i++) acc += x[n * 15 + i] * w[i * 64 + o];
    acc += z[n] * w[15 * 64 + o];
    s[idx] = fmaxf(acc, 0.0f);
}

__global__ void k_deg(const int* __restrict__ dstI, float* __restrict__ deg) {
    int e = blockIdx.x * 256 + threadIdx.x;
    if (e < NE) atomicAdd(&deg[dstI[e]], 1.0f);
}

// s -> f16 copy (4 elements/thread)
__global__ void k_s16(const float* __restrict__ s, _Float16* __restrict__ s16) {
    int i = blockIdx.x * 256 + threadIdx.x;  // NN*16 exact
    float4 v = ((const float4*)s)[i];
    h4 o = { (_Float16)v.x, (_Float16)v.y, (_Float16)v.z, (_Float16)v.w };
    *((h4*)s16 + i) = o;
}

// edge MLP layer 1 fused with transpose to f16: hidT[h][e], h=0..131
__global__ void k_emlp_t(const float* __restrict__ ea, const float* __restrict__ w1,
                         const float* __restrict__ b1, _Float16* __restrict__ hidT) {
    __shared__ _Float16 hl[132][64];
    int t = threadIdx.x;
    int e0 = blockIdx.x * 64;
    int e_l = t & 63, w = t >> 6;
    int e = e0 + e_l;
    float a0 = 0, a1 = 0, a2 = 0, a3 = 0, a4 = 0;
    if (e < NE) {
        a0 = ea[e * 5 + 0]; a1 = ea[e * 5 + 1]; a2 = ea[e * 5 + 2];
        a3 = ea[e * 5 + 3]; a4 = ea[e * 5 + 4];
    }
    for (int h = w * 32; h < w * 32 + 32; h++) {
        float acc = b1[h];
        acc += a0 * w1[0 * 128 + h] + a1 * w1[1 * 128 + h] + a2 * w1[2 * 128 + h]
             + a3 * w1[3 * 128 + h] + a4 * w1[4 * 128 + h];
        hl[h][e_l] = (_Float16)fmaxf(acc, 0.0f);
    }
    if (t < 64) hl[128][t] = (_Float16)1.0f;
    else if (t < 128) hl[129][t - 64] = (_Float16)0.0f;
    else if (t < 192) hl[130][t - 128] = (_Float16)0.0f;
    else hl[131][t - 192] = (_Float16)0.0f;
    __syncthreads();
#pragma unroll
    for (int it = 0; it < 33; it++) {
        int idx = it * 256 + t;
        int h = idx >> 6, el = idx & 63;
        hidT[(size_t)h * EPAD + e0 + el] = hl[h][el];
    }
}

// Pre-arrange B = [w2 ; b2 ; 0] (shape [8448,64]) into MFMA-fragment order
__global__ void k_prep_B(const float* __restrict__ w2, const float* __restrict__ b2,
                         _Float16* __restrict__ Bp) {
    int g = blockIdx.x * 256 + threadIdx.x;   // KCH*4*64 = 67584 exact
    int l = g & 63, tt = (g >> 6) & 3, c = g >> 8;
    int n = tt * 16 + (l & 15);
    int kb = c * 32 + (l >> 4) * 8;
    h8 v;
#pragma unroll
    for (int j = 0; j < 8; j++) {
        int k = kb + j;
        float f = 0.0f;
        if (k < 8192) f = w2[(size_t)k * 64 + n];
        else if (k < 8256) f = b2[(k - 8192) * 64 + n];
        v[j] = (_Float16)f;
    }
    *((h8*)Bp + g) = v;
}

// Pre-arrange combine weights into MFMA B-fragment layout (f16):
// units 0..7:  R  (conv_root [k][n], k=64, n=64; 4 nt x 2 kc)
// units 8..31: Wi (B[k][o]=gru_wi[o*64+k], o=192; 12 nt x 2 kc)
// units 32..55:Wh (B[k][o]=gru_wh[o*64+k])
__global__ void k_prep_W(const float* __restrict__ conv_root,
                         const float* __restrict__ gru_wi,
                         const float* __restrict__ gru_wh,
                         _Float16* __restrict__ Bw) {
    int g = blockIdx.x * 256 + threadIdx.x;   // 56*64 = 3584
    if (g >= 56 * 64) return;
    int l = g & 63, unit = g >> 6;
    int kb = ((unit & 1) * 32) + (l >> 4) * 8;   // kc = unit&1
    h8 v;
    if (unit < 8) {
        int nt = unit >> 1;
        int n = nt * 16 + (l & 15);
#pragma unroll
        for (int j = 0; j < 8; j++) v[j] = (_Float16)conv_root[(kb + j) * 64 + n];
    } else if (unit < 32) {
        int nt = (unit - 8) >> 1;
        int o = nt * 16 + (l & 15);
#pragma unroll
        for (int j = 0; j < 8; j++) v[j] = (_Float16)gru_wi[o * 64 + kb + j];
    } else {
        int nt = (unit - 32) >> 1;
        int o = nt * 16 + (l & 15);
#pragma unroll
        for (int j = 0; j < 8; j++) v[j] = (_Float16)gru_wh[o * 64 + kb + j];
    }
    *((h8*)Bw + g) = v;
}

// Fused NNConv message: msg[e,:] = (hid[e]⊗s[src[e]]) @ B, atomic-scatter to aggr[dst[e]]
__global__ __launch_bounds__(256) void k_fused(
        const _Float16* __restrict__ s16, const _Float16* __restrict__ hidT,
        const _Float16* __restrict__ Bp, const int* __restrict__ srcI,
        const int* __restrict__ dstI, float* __restrict__ aggr) {
    __shared__ uint4 Bl[2048];            // 32 KB
    __shared__ _Float16 hl[4][128];
    int t = threadIdx.x, w = t >> 6, lane = t & 63;
    int m = lane & 15, q = lane >> 4;
    int e_blk = blockIdx.x * 128;
    int ew0 = e_blk + w * 32;

    h8 slo[2], shi[2];
#pragma unroll
    for (int mt = 0; mt < 2; mt++) {
        int e = ew0 + mt * 16 + m;
        int src = (e < NE) ? srcI[e] : 0;
        const _Float16* sp = s16 + (size_t)src * 64;
        slo[mt] = *(const h8*)(sp + q * 8);
        shi[mt] = *(const h8*)(sp + 32 + q * 8);
    }
    f4 acc[2][4];
#pragma unroll
    for (int mt = 0; mt < 2; mt++)
#pragma unroll
        for (int nt = 0; nt < 4; nt++) acc[mt][nt] = (f4){0.f, 0.f, 0.f, 0.f};

    for (int sc = 0; sc < 33; sc++) {
        __syncthreads();
        const uint4* bsrc = (const uint4*)Bp + (size_t)sc * 2048;
#pragma unroll
        for (int r = 0; r < 8; r++) Bl[r * 256 + t] = bsrc[r * 256 + t];
        {
            int h_l = t >> 6, e2 = (t & 63) * 2;
            unsigned v = *(const unsigned*)(hidT + (size_t)(sc * 4 + h_l) * EPAD + e_blk + e2);
            *((unsigned*)&hl[h_l][0] + (t & 63)) = v;
        }
        __syncthreads();
#pragma unroll
        for (int cc = 0; cc < 8; cc++) {
            h8 b0 = *(const h8*)&Bl[(cc * 4 + 0) * 64 + lane];
            h8 b1 = *(const h8*)&Bl[(cc * 4 + 1) * 64 + lane];
            h8 b2 = *(const h8*)&Bl[(cc * 4 + 2) * 64 + lane];
            h8 b3 = *(const h8*)&Bl[(cc * 4 + 3) * 64 + lane];
            int hli = cc >> 1;
#pragma unroll
            for (int mt = 0; mt < 2; mt++) {
                _Float16 hv = hl[hli][w * 32 + mt * 16 + m];
                h8 a = ((cc & 1) ? shi[mt] : slo[mt]) * hv;
                acc[mt][0] = __builtin_amdgcn_mfma_f32_16x16x32_f16(a, b0, acc[mt][0], 0, 0, 0);
                acc[mt][1] = __builtin_amdgcn_mfma_f32_16x16x32_f16(a, b1, acc[mt][1], 0, 0, 0);
                acc[mt][2] = __builtin_amdgcn_mfma_f32_16x16x32_f16(a, b2, acc[mt][2], 0, 0, 0);
                acc[mt][3] = __builtin_amdgcn_mfma_f32_16x16x32_f16(a, b3, acc[mt][3], 0, 0, 0);
            }
        }
    }
#pragma unroll
    for (int mt = 0; mt < 2; mt++) {
        int eb = ew0 + mt * 16 + q * 4;
#pragma unroll
        for (int r = 0; r < 4; r++) {
            int e = eb + r;
            if (e < NE) {
                int d = dstI[e];
                float* ap = aggr + (size_t)d * 64 + m;
                atomicAdd(ap + 0,  acc[mt][0][r]);
                atomicAdd(ap + 16, acc[mt][1][r]);
                atomicAdd(ap + 32, acc[mt][2][r]);
                atomicAdd(ap + 48, acc[mt][3][r]);
            }
        }
    }
}

// MFMA NNConv-root + GRU combine. Block=256 (4 waves), 64 nodes/block.
// X = s@R; GH = h@Wh^T; m = relu(X + aggr/deg + cb); GI = m@Wi^T; gates; update s,s16.
__global__ __launch_bounds__(256) void k_combine2(
        float* __restrict__ s, _Float16* __restrict__ s16,
        const float* __restrict__ aggr, const float* __restrict__ deg,
        const _Float16* __restrict__ Bw, const float* __restrict__ cb,
        const float* __restrict__ bi, const float* __restrict__ bh) {
    __shared__ _Float16 ml[4][16][72];    // padded stride 72
    int t = threadIdx.x, w = t >> 6, lane = t & 63;
    int m = lane & 15, q = lane >> 4;
    int nb = blockIdx.x * 64 + w * 16;    // wave's 16-node tile

    // A-fragments of s16 (k = 0..31 in sa0, 32..63 in sa1)
    h8 sa0, sa1;
    {
        int node = nb + m; if (node >= NN) node = NN - 1;
        const _Float16* sp = s16 + (size_t)node * 64;
        sa0 = *(const h8*)(sp + q * 8);
        sa1 = *(const h8*)(sp + 32 + q * 8);
    }
    const h8* BW = (const h8*)Bw;

    // stage A: X = s@R (4 nt), GH = s@Wh (12 nt)
    f4 X[4], GH[12];
#pragma unroll
    for (int nt = 0; nt < 4; nt++) {
        X[nt] = (f4){0.f, 0.f, 0.f, 0.f};
        X[nt] = __builtin_amdgcn_mfma_f32_16x16x32_f16(sa0, BW[(nt * 2 + 0) * 64 + lane], X[nt], 0, 0, 0);
        X[nt] = __builtin_amdgcn_mfma_f32_16x16x32_f16(sa1, BW[(nt * 2 + 1) * 64 + lane], X[nt], 0, 0, 0);
    }
#pragma unroll
    for (int nt = 0; nt < 12; nt++) {
        GH[nt] = (f4){0.f, 0.f, 0.f, 0.f};
        GH[nt] = __builtin_amdgcn_mfma_f32_16x16x32_f16(sa0, BW[(32 + nt * 2 + 0) * 64 + lane], GH[nt], 0, 0, 0);
        GH[nt] = __builtin_amdgcn_mfma_f32_16x16x32_f16(sa1, BW[(32 + nt * 2 + 1) * 64 + lane], GH[nt], 0, 0, 0);
    }
    // m = relu(X + aggr/deg + cb) -> LDS (A-layout staging)
#pragma unroll
    for (int r = 0; r < 4; r++) {
        int node = nb + q * 4 + r; if (node >= NN) node = NN - 1;
        float dn = fmaxf(deg[node], 1.0f);
#pragma unroll
        for (int nt = 0; nt < 4; nt++) {
            int o = nt * 16 + m;
            float mv = X[nt][r] + aggr[(size_t)node * 64 + o] / dn + cb[o];
            ml[w][q * 4 + r][o] = (_Float16)fmaxf(mv, 0.0f);
        }
    }
    __syncthreads();
    h8 ma0 = *(const h8*)&ml[w][m][q * 8];
    h8 ma1 = *(const h8*)&ml[w][m][32 + q * 8];

    // stage B: GI = m@Wi (12 nt)
    f4 GI[12];
#pragma unroll
    for (int nt = 0; nt < 12; nt++) {
        GI[nt] = (f4){0.f, 0.f, 0.f, 0.f};
        GI[nt] = __builtin_amdgcn_mfma_f32_16x16x32_f16(ma0, BW[(8 + nt * 2 + 0) * 64 + lane], GI[nt], 0, 0, 0);
        GI[nt] = __builtin_amdgcn_mfma_f32_16x16x32_f16(ma1, BW[(8 + nt * 2 + 1) * 64 + lane], GI[nt], 0, 0, 0);
    }
    // epilogue: gates + state update
#pragma unroll
    for (int og = 0; og < 4; og++) {
        int o = og * 16 + m;
        float bir = bi[o],       bhr = bh[o];
        float biz = bi[64 + o],  bhz = bh[64 + o];
        float bin = bi[128 + o], bhn = bh[128 + o];
#pragma unroll
        for (int r = 0; r < 4; r++) {
            int node = nb + q * 4 + r;
            if (node >= NN) continue;
            float rr = sigf(GI[og][r] + bir + GH[og][r] + bhr);
            float zz = sigf(GI[4 + og][r] + biz + GH[4 + og][r] + bhz);
            float ng = tanhf(GI[8 + og][r] + bin + rr * (GH[8 + og][r] + bhn));
            float hold = s[(size_t)node * 64 + o];
            float hnew = (1.0f - zz) * ng + zz * hold;
            s[(size_t)node * 64 + o] = hnew;
            s16[(size_t)node * 64 + o] = (_Float16)hnew;
        }
    }
}

// LSTM cell, one block(256) per graph
__global__ void k_lstm(const float* __restrict__ q_star, float* __restrict__ hh,
                       float* __restrict__ cc, const float* __restrict__ LiT,
                       const float* __restrict__ LhT, const float* __restrict__ bi,
                       const float* __restrict__ bh) {
    __shared__ float qs[128], hv[64], g[256];
    int b = blockIdx.x, t = threadIdx.x;
    if (t < 128) qs[t] = q_star[b * 128 + t];
    else if (t < 192) hv[t - 128] = hh[b * 64 + t - 128];
    __syncthreads();
    float acc = bi[t] + bh[t];
    for (int k = 0; k < 128; k++) acc += qs[k] * LiT[k * 256 + t];
    for (int k = 0; k < 64; k++) acc += hv[k] * LhT[k * 256 + t];
    g[t] = acc;
    __syncthreads();
    if (t < 64) {
        float c_new = sigf(g[64 + t]) * cc[b * 64 + t] + sigf(g[t]) * tanhf(g[128 + t]);
        cc[b * 64 + t] = c_new;
        hh[b * 64 + t] = sigf(g[192 + t]) * tanhf(c_new);
    }
}

// e[n] = dot(out[n], q[batch[n]]); segment-max via order-preserving uint atomicMax
__global__ void k_dot(const float* __restrict__ s, const float* __restrict__ hh,
                      const int* __restrict__ batch, float* __restrict__ e_v,
                      unsigned* __restrict__ emax) {
    int n = blockIdx.x * 256 + threadIdx.x;
    if (n >= NN) return;
    int b = batch[n];
    const float4* sp = (const float4*)&s[(size_t)n * 64];
    const float4* qp = (const float4*)&hh[(size_t)b * 64];
    float acc = 0;
#pragma unroll
    for (int i = 0; i < 16; i++) {
        float4 a = sp[i], q = qp[i];
        acc += a.x * q.x + a.y * q.y + a.z * q.z + a.w * q.w;
    }
    e_v[n] = acc;
    atomicMax(&emax[b], f2enc(acc));
}

// a = exp(e - emax); asum += a; r_pool += a*out
__global__ void k_attn(const float* __restrict__ s, const float* __restrict__ e_v,
                       const unsigned* __restrict__ emax, const int* __restrict__ batch,
                       float* __restrict__ asum, float* __restrict__ r_pool) {
    int idx = blockIdx.x * 256 + threadIdx.x;  // NN*64 exact
    int n = idx >> 6, o = idx & 63;
    int b = batch[n];
    float a = __expf(e_v[n] - enc2f(emax[b]));
    atomicAdd(&r_pool[(size_t)b * 64 + o], a * s[idx]);
    if (o == 0) atomicAdd(&asum[b], a);
}

__global__ void k_qstar(float* __restrict__ q_star, const float* __restrict__ hh,
                        const float* __restrict__ r_pool, const float* __restrict__ asum) {
    int idx = blockIdx.x * 256 + threadIdx.x;  // NG*128 exact
    int b = idx >> 7, j = idx & 127;
    q_star[idx] = (j < 64) ? hh[b * 64 + j]
                           : r_pool[b * 64 + j - 64] / (asum[b] + 1e-16f);
}

// y[b] = relu(q_star @ lin1 + b1) @ lin2 + b2 ; one wave per graph
__global__ void k_final(const float* __restrict__ q_star, const float* __restrict__ w1,
                        const float* __restrict__ b1, const float* __restrict__ w2,
                        const float* __restrict__ b2, float* __restrict__ y) {
    __shared__ float qs[128];
    int b = blockIdx.x, t = threadIdx.x;  // 64 threads
    qs[t] = q_star[b * 128 + t];
    qs[64 + t] = q_star[b * 128 + 64 + t];
    __syncthreads();
    float acc = b1[t];
    for (int k = 0; k < 128; k++) acc += qs[k] * w1[k * 64 + t];
    float hid = fmaxf(acc, 0.0f) * w2[t];
#pragma unroll
    for (int off = 32; off; off >>= 1) hid += __shfl_down(hid, off, 64);
    if (t == 0) y[b] = hid + b2[0];
}

static inline void zero_f(float* p, size_t nfloats, hipStream_t stream) {
    int n4 = (int)(nfloats / 4);
    k_zero4<<<(n4 + 255) / 256, 256, 0, stream>>>((float4*)p, n4);
}

extern "C" void kernel_launch(void* const* d_in, const int* in_sizes, int n_in,
                              void* d_out, int out_size, void* d_ws, size_t ws_size,
                              hipStream_t stream) {
    const float* x       = (const float*)d_in[0];
    const float* z       = (const float*)d_in[1];
    const float* ea      = (const float*)d_in[2];
    const float* lin0_w  = (const float*)d_in[3];
    const float* lin0_b  = (const float*)d_in[4];
    const float* emlp_w1 = (const float*)d_in[5];
    const float* emlp_b1 = (const float*)d_in[6];
    const float* emlp_w2 = (const float*)d_in[7];
    const float* emlp_b2 = (const float*)d_in[8];
    const float* conv_r  = (const float*)d_in[9];
    const float* conv_b  = (const float*)d_in[10];
    const float* gru_wi  = (const float*)d_in[11];
    const float* gru_wh  = (const float*)d_in[12];
    const float* gru_bi  = (const float*)d_in[13];
    const float* gru_bh  = (const float*)d_in[14];
    const float* lstm_wi = (const float*)d_in[15];
    const float* lstm_wh = (const float*)d_in[16];
    const float* lstm_bi = (const float*)d_in[17];
    const float* lstm_bh = (const float*)d_in[18];
    const float* lin1_w  = (const float*)d_in[19];
    const float* lin1_b  = (const float*)d_in[20];
    const float* lin2_w  = (const float*)d_in[21];
    const float* lin2_b  = (const float*)d_in[22];
    const int* eidx      = (const int*)d_in[23];
    const int* batch     = (const int*)d_in[24];
    const int* srcI = eidx;
    const int* dstI = eidx + NE;
    float* y = (float*)d_out;

    char* w = (char*)d_ws;
    size_t off = 0;
    auto alloc = [&](size_t bytes) -> void* {
        void* p = w + off;
        off += (bytes + 255) & ~(size_t)255;
        return p;
    };
    float* s      = (float*)alloc((size_t)NN * 64 * 4);
    float* aggr   = (float*)alloc((size_t)NN * 64 * 4);
    float* deg    = (float*)alloc((size_t)NN * 4);
    float* e_v    = (float*)alloc((size_t)NN * 4);
    // contiguous zero region: emax(10240B pad) | asum(10240B pad) | r_pool(640000B)
    unsigned* emax= (unsigned*)alloc((size_t)NG * 4);
    float* asum   = (float*)alloc((size_t)NG * 4);
    float* r_pool = (float*)alloc((size_t)NG * 64 * 4);
    // contiguous zero region: q_star | hh | cc (all 256-multiples)
    float* q_star = (float*)alloc((size_t)NG * 128 * 4);
    float* hh     = (float*)alloc((size_t)NG * 64 * 4);
    float* cc     = (float*)alloc((size_t)NG * 64 * 4);
    float* LiT    = (float*)alloc(256 * 128 * 4);
    float* LhT    = (float*)alloc(256 * 64 * 4);
    _Float16* s16 = (_Float16*)alloc((size_t)NN * 64 * 2);
    _Float16* hidT= (_Float16*)alloc((size_t)132 * EPAD * 2);
    _Float16* Bp  = (_Float16*)alloc((size_t)KCH * 4 * 64 * 8 * 2);
    _Float16* Bw  = (_Float16*)alloc((size_t)56 * 64 * 8 * 2);
    (void)ws_size;  // ~64 MB total, well under proven capacity

    // LSTM weight transposes + combine-weight fragment prep
    k_transpose<<<(256 * 128 + 255) / 256, 256, 0, stream>>>(LiT, lstm_wi, 256, 128);
    k_transpose<<<(256 * 64 + 255) / 256, 256, 0, stream>>>(LhT, lstm_wh, 256, 64);
    k_prep_W<<<14, 256, 0, stream>>>(conv_r, gru_wi, gru_wh, Bw);

    // node embedding, degree, edge-MLP layer 1 (-> hidT f16), B prep
    k_lin0<<<NN * 64 / 256, 256, 0, stream>>>(x, z, lin0_w, lin0_b, s);
    k_s16<<<NN * 16 / 256, 256, 0, stream>>>(s, s16);
    zero_f(deg, NN, stream);
    k_deg<<<(NE + 255) / 256, 256, 0, stream>>>(dstI, deg);
    k_emlp_t<<<EPAD / 64, 256, 0, stream>>>(ea, emlp_w1, emlp_b1, hidT);
    k_prep_B<<<KCH * 4 * 64 / 256, 256, 0, stream>>>(emlp_w2, emlp_b2, Bp);

    // 5 message-passing + GRU steps
    for (int step = 0; step < 5; step++) {
        zero_f(aggr, (size_t)NN * 64, stream);
        k_fused<<<EPAD / 128, 256, 0, stream>>>(s16, hidT, Bp, srcI, dstI, aggr);
        k_combine2<<<(NN + 63) / 64, 256, 0, stream>>>(s, s16, aggr, deg, Bw,
                                                       conv_b, gru_bi, gru_bh);
    }

    // Set2Set
    zero_f(q_star, (size_t)NG * 128 + NG * 64 + NG * 64, stream);
    for (int it = 0; it < 5; it++) {
        k_lstm<<<NG, 256, 0, stream>>>(q_star, hh, cc, LiT, LhT, lstm_bi, lstm_bh);
        zero_f((float*)emax, (10240 + 10240 + 640000) / 4, stream);
        k_dot<<<(NN + 255) / 256, 256, 0, stream>>>(s, hh, batch, e_v, emax);
        k_attn<<<NN * 64 / 256, 256, 0, stream>>>(s, e_v, emax, batch, asum, r_pool);
        k_qstar<<<NG * 128 / 256, 256, 0, stream>>>(q_star, hh, r_pool, asum);
    }
    k_final<<<NG, 64, 0, stream>>>(q_star, lin1_w, lin1_b, lin2_w, lin2_b, y);
}

// Round 5
// 1061.672 us; speedup vs baseline: 10.5987x; 1.2174x over previous
//
#include <hip/hip_runtime.h>
#include <hip/hip_bf16.h>

#define NN 50000      // nodes
#define NE 100000     // edges
#define NG 2500       // graphs
#define WW 128        // edge-mlp width
#define EPAD 100096   // 782 blocks * 128 edges
#define KCH 264       // K chunks of 32: 8448 = 132 h-rows * 64 (128 hid + 1 bias + 3 zero)

typedef _Float16 h8 __attribute__((ext_vector_type(8)));
typedef _Float16 h4 __attribute__((ext_vector_type(4)));
typedef float    f4 __attribute__((ext_vector_type(4)));

#define GLOAD_LDS16(g, l) __builtin_amdgcn_global_load_lds( \
    (const __attribute__((address_space(1))) void*)(g),     \
    (__attribute__((address_space(3))) void*)(l), 16, 0, 0)

__device__ __forceinline__ float sigf(float x) { return 1.0f / (1.0f + __expf(-x)); }

// zero n4 float4's
__global__ void k_zero4(float4* __restrict__ p, int n4) {
    int i = blockIdx.x * 256 + threadIdx.x;
    if (i < n4) p[i] = make_float4(0.f, 0.f, 0.f, 0.f);
}

// dst[c*rows + r] = src[r*cols + c]
__global__ void k_transpose(float* dst, const float* src, int rows, int cols) {
    int idx = blockIdx.x * 256 + threadIdx.x;
    if (idx >= rows * cols) return;
    int r = idx / cols, c = idx % cols;
    dst[c * rows + r] = src[idx];
}

// s[n,o] = relu([x|z] @ lin0_w + b)
__global__ void k_lin0(const float* __restrict__ x, const float* __restrict__ z,
                       const float* __restrict__ w, const float* __restrict__ b,
                       float* __restrict__ s) {
    int idx = blockIdx.x * 256 + threadIdx.x;  // NN*64 exact
    int n = idx >> 6, o = idx & 63;
    float acc = b[o];
#pragma unroll
    for (int i = 0; i < 15; i++) acc += x[n * 15 + i] * w[i * 64 + o];
    acc += z[n] * w[15 * 64 + o];
    s[idx] = fmaxf(acc, 0.0f);
}

__global__ void k_deg(const int* __restrict__ dstI, float* __restrict__ deg) {
    int e = blockIdx.x * 256 + threadIdx.x;
    if (e < NE) atomicAdd(&deg[dstI[e]], 1.0f);
}

// s -> f16 copy (prologue only; steady-state s16 written by k_combine2)
__global__ void k_s16(const float* __restrict__ s, _Float16* __restrict__ s16) {
    int i = blockIdx.x * 256 + threadIdx.x;  // NN*16 exact
    float4 v = ((const float4*)s)[i];
    h4 o = { (_Float16)v.x, (_Float16)v.y, (_Float16)v.z, (_Float16)v.w };
    *((h4*)s16 + i) = o;
}

// gstart[g] = first node n with batch[n] >= g (batch sorted); gstart[NG] = NN
__global__ void k_gstart(const int* __restrict__ batch, int* __restrict__ gstart) {
    int n = blockIdx.x * 256 + threadIdx.x;
    if (n > NN) return;
    int b1 = (n < NN) ? batch[n] : NG;
    int b0 = (n == 0) ? -1 : batch[n - 1];
    for (int g = b0 + 1; g <= b1; g++) gstart[g] = n;
}

// edge MLP layer 1 fused with transpose to f16: hidT[h][e], h=0..131
__global__ void k_emlp_t(const float* __restrict__ ea, const float* __restrict__ w1,
                         const float* __restrict__ b1, _Float16* __restrict__ hidT) {
    __shared__ _Float16 hl[132][64];
    int t = threadIdx.x;
    int e0 = blockIdx.x * 64;
    int e_l = t & 63, w = t >> 6;
    int e = e0 + e_l;
    float a0 = 0, a1 = 0, a2 = 0, a3 = 0, a4 = 0;
    if (e < NE) {
        a0 = ea[e * 5 + 0]; a1 = ea[e * 5 + 1]; a2 = ea[e * 5 + 2];
        a3 = ea[e * 5 + 3]; a4 = ea[e * 5 + 4];
    }
    for (int h = w * 32; h < w * 32 + 32; h++) {
        float acc = b1[h];
        acc += a0 * w1[0 * 128 + h] + a1 * w1[1 * 128 + h] + a2 * w1[2 * 128 + h]
             + a3 * w1[3 * 128 + h] + a4 * w1[4 * 128 + h];
        hl[h][e_l] = (_Float16)fmaxf(acc, 0.0f);
    }
    if (t < 64) hl[128][t] = (_Float16)1.0f;
    else if (t < 128) hl[129][t - 64] = (_Float16)0.0f;
    else if (t < 192) hl[130][t - 128] = (_Float16)0.0f;
    else hl[131][t - 192] = (_Float16)0.0f;
    __syncthreads();
#pragma unroll
    for (int it = 0; it < 33; it++) {
        int idx = it * 256 + t;
        int h = idx >> 6, el = idx & 63;
        hidT[(size_t)h * EPAD + e0 + el] = hl[h][el];
    }
}

// Pre-arrange B = [w2 ; b2 ; 0] (shape [8448,64]) into MFMA-fragment order
__global__ void k_prep_B(const float* __restrict__ w2, const float* __restrict__ b2,
                         _Float16* __restrict__ Bp) {
    int g = blockIdx.x * 256 + threadIdx.x;   // KCH*4*64 = 67584 exact
    int l = g & 63, tt = (g >> 6) & 3, c = g >> 8;
    int n = tt * 16 + (l & 15);
    int kb = c * 32 + (l >> 4) * 8;
    h8 v;
#pragma unroll
    for (int j = 0; j < 8; j++) {
        int k = kb + j;
        float f = 0.0f;
        if (k < 8192) f = w2[(size_t)k * 64 + n];
        else if (k < 8256) f = b2[(k - 8192) * 64 + n];
        v[j] = (_Float16)f;
    }
    *((h8*)Bp + g) = v;
}

// Pre-arrange combine weights into MFMA B-fragment layout (f16)
__global__ void k_prep_W(const float* __restrict__ conv_root,
                         const float* __restrict__ gru_wi,
                         const float* __restrict__ gru_wh,
                         _Float16* __restrict__ Bw) {
    int g = blockIdx.x * 256 + threadIdx.x;   // 56*64 = 3584
    if (g >= 56 * 64) return;
    int l = g & 63, unit = g >> 6;
    int kb = ((unit & 1) * 32) + (l >> 4) * 8;
    h8 v;
    if (unit < 8) {
        int nt = unit >> 1;
        int n = nt * 16 + (l & 15);
#pragma unroll
        for (int j = 0; j < 8; j++) v[j] = (_Float16)conv_root[(kb + j) * 64 + n];
    } else if (unit < 32) {
        int nt = (unit - 8) >> 1;
        int o = nt * 16 + (l & 15);
#pragma unroll
        for (int j = 0; j < 8; j++) v[j] = (_Float16)gru_wi[o * 64 + kb + j];
    } else {
        int nt = (unit - 32) >> 1;
        int o = nt * 16 + (l & 15);
#pragma unroll
        for (int j = 0; j < 8; j++) v[j] = (_Float16)gru_wh[o * 64 + kb + j];
    }
    *((h8*)Bw + g) = v;
}

// Fused NNConv message. v2: 2 waves/block, 64 edges/wave (4 m-tiles), 128 edges/block.
// Each B fragment LDS read feeds 4 MFMA; B staged via async global_load_lds.
__global__ __launch_bounds__(128, 2) void k_fused(
        const _Float16* __restrict__ s16, const _Float16* __restrict__ hidT,
        const _Float16* __restrict__ Bp, const int* __restrict__ srcI,
        const int* __restrict__ dstI, float* __restrict__ aggr) {
    __shared__ uint4 Bl[2048];            // 32 KB: 8 chunks x 4 nt x 64 lanes
    __shared__ _Float16 hle[128][4];      // per-edge h4 (this sc's 4 h-rows)
    int t = threadIdx.x, w = t >> 6, lane = t & 63;
    int m = lane & 15, q = lane >> 4;
    int e_blk = blockIdx.x * 128;
    int ew0 = e_blk + w * 64;             // wave's 64 edges

    // s A-fragments: [mt][k-half], reused across entire K loop
    h8 sA[4][2];
#pragma unroll
    for (int mt = 0; mt < 4; mt++) {
        int e = ew0 + mt * 16 + m;
        int src = (e < NE) ? srcI[e] : 0;
        const _Float16* sp = s16 + (size_t)src * 64;
        sA[mt][0] = *(const h8*)(sp + q * 8);
        sA[mt][1] = *(const h8*)(sp + 32 + q * 8);
    }
    f4 acc[4][4];
#pragma unroll
    for (int mt = 0; mt < 4; mt++)
#pragma unroll
        for (int nt = 0; nt < 4; nt++) acc[mt][nt] = (f4){0.f, 0.f, 0.f, 0.f};

    for (int sc = 0; sc < 33; sc++) {
        __syncthreads();                  // prior reads done before overwrite
        const uint4* bsrc = (const uint4*)Bp + (size_t)sc * 2048;
#pragma unroll
        for (int r = 0; r < 16; r++) {    // 2048 uint4 / 128 thr, async DMA to LDS
            int idx = r * 128 + t;
            GLOAD_LDS16(bsrc + idx, Bl + idx);
        }
        {   // hid rows sc*4..sc*4+3 for this block's 128 edges, per-edge h4
            const _Float16* hp = hidT + (size_t)(sc * 4) * EPAD + e_blk + t;
            h4 hv4;
            hv4[0] = hp[0];
            hv4[1] = hp[EPAD];
            hv4[2] = hp[2 * (size_t)EPAD];
            hv4[3] = hp[3 * (size_t)EPAD];
            *(h4*)&hle[t][0] = hv4;
        }
        __syncthreads();                  // drains vmcnt (DMA) + lgkm
        h4 hf[4];
#pragma unroll
        for (int mt = 0; mt < 4; mt++)
            hf[mt] = *(const h4*)&hle[w * 64 + mt * 16 + m][0];
#pragma unroll
        for (int cc = 0; cc < 8; cc++) {
            h8 b0 = *(const h8*)&Bl[(cc * 4 + 0) * 64 + lane];
            h8 b1 = *(const h8*)&Bl[(cc * 4 + 1) * 64 + lane];
            h8 b2 = *(const h8*)&Bl[(cc * 4 + 2) * 64 + lane];
            h8 b3 = *(const h8*)&Bl[(cc * 4 + 3) * 64 + lane];
            int hi = cc >> 1, kh = cc & 1;
#pragma unroll
            for (int mt = 0; mt < 4; mt++) {
                h8 a = sA[mt][kh] * hf[mt][hi];
                acc[mt][0] = __builtin_amdgcn_mfma_f32_16x16x32_f16(a, b0, acc[mt][0], 0, 0, 0);
                acc[mt][1] = __builtin_amdgcn_mfma_f32_16x16x32_f16(a, b1, acc[mt][1], 0, 0, 0);
                acc[mt][2] = __builtin_amdgcn_mfma_f32_16x16x32_f16(a, b2, acc[mt][2], 0, 0, 0);
                acc[mt][3] = __builtin_amdgcn_mfma_f32_16x16x32_f16(a, b3, acc[mt][3], 0, 0, 0);
            }
        }
    }
    // epilogue: C/D layout col=lane&15, row=q*4+reg
#pragma unroll
    for (int mt = 0; mt < 4; mt++) {
        int eb = ew0 + mt * 16 + q * 4;
#pragma unroll
        for (int r = 0; r < 4; r++) {
            int e = eb + r;
            if (e < NE) {
                int d = dstI[e];
                float* ap = aggr + (size_t)d * 64 + m;
                atomicAdd(ap + 0,  acc[mt][0][r]);
                atomicAdd(ap + 16, acc[mt][1][r]);
                atomicAdd(ap + 32, acc[mt][2][r]);
                atomicAdd(ap + 48, acc[mt][3][r]);
            }
        }
    }
}

// MFMA NNConv-root + GRU combine. Block=256 (4 waves), 64 nodes/block.
__global__ __launch_bounds__(256) void k_combine2(
        float* __restrict__ s, _Float16* __restrict__ s16,
        const float* __restrict__ aggr, const float* __restrict__ deg,
        const _Float16* __restrict__ Bw, const float* __restrict__ cb,
        const float* __restrict__ bi, const float* __restrict__ bh) {
    __shared__ _Float16 ml[4][16][72];
    int t = threadIdx.x, w = t >> 6, lane = t & 63;
    int m = lane & 15, q = lane >> 4;
    int nb = blockIdx.x * 64 + w * 16;

    h8 sa0, sa1;
    {
        int node = nb + m; if (node >= NN) node = NN - 1;
        const _Float16* sp = s16 + (size_t)node * 64;
        sa0 = *(const h8*)(sp + q * 8);
        sa1 = *(const h8*)(sp + 32 + q * 8);
    }
    const h8* BW = (const h8*)Bw;

    f4 X[4], GH[12];
#pragma unroll
    for (int nt = 0; nt < 4; nt++) {
        X[nt] = (f4){0.f, 0.f, 0.f, 0.f};
        X[nt] = __builtin_amdgcn_mfma_f32_16x16x32_f16(sa0, BW[(nt * 2 + 0) * 64 + lane], X[nt], 0, 0, 0);
        X[nt] = __builtin_amdgcn_mfma_f32_16x16x32_f16(sa1, BW[(nt * 2 + 1) * 64 + lane], X[nt], 0, 0, 0);
    }
#pragma unroll
    for (int nt = 0; nt < 12; nt++) {
        GH[nt] = (f4){0.f, 0.f, 0.f, 0.f};
        GH[nt] = __builtin_amdgcn_mfma_f32_16x16x32_f16(sa0, BW[(32 + nt * 2 + 0) * 64 + lane], GH[nt], 0, 0, 0);
        GH[nt] = __builtin_amdgcn_mfma_f32_16x16x32_f16(sa1, BW[(32 + nt * 2 + 1) * 64 + lane], GH[nt], 0, 0, 0);
    }
#pragma unroll
    for (int r = 0; r < 4; r++) {
        int node = nb + q * 4 + r; if (node >= NN) node = NN - 1;
        float dn = fmaxf(deg[node], 1.0f);
#pragma unroll
        for (int nt = 0; nt < 4; nt++) {
            int o = nt * 16 + m;
            float mv = X[nt][r] + aggr[(size_t)node * 64 + o] / dn + cb[o];
            ml[w][q * 4 + r][o] = (_Float16)fmaxf(mv, 0.0f);
        }
    }
    __syncthreads();
    h8 ma0 = *(const h8*)&ml[w][m][q * 8];
    h8 ma1 = *(const h8*)&ml[w][m][32 + q * 8];

    f4 GI[12];
#pragma unroll
    for (int nt = 0; nt < 12; nt++) {
        GI[nt] = (f4){0.f, 0.f, 0.f, 0.f};
        GI[nt] = __builtin_amdgcn_mfma_f32_16x16x32_f16(ma0, BW[(8 + nt * 2 + 0) * 64 + lane], GI[nt], 0, 0, 0);
        GI[nt] = __builtin_amdgcn_mfma_f32_16x16x32_f16(ma1, BW[(8 + nt * 2 + 1) * 64 + lane], GI[nt], 0, 0, 0);
    }
#pragma unroll
    for (int og = 0; og < 4; og++) {
        int o = og * 16 + m;
        float bir = bi[o],       bhr = bh[o];
        float biz = bi[64 + o],  bhz = bh[64 + o];
        float bin = bi[128 + o], bhn = bh[128 + o];
#pragma unroll
        for (int r = 0; r < 4; r++) {
            int node = nb + q * 4 + r;
            if (node >= NN) continue;
            float rr = sigf(GI[og][r] + bir + GH[og][r] + bhr);
            float zz = sigf(GI[4 + og][r] + biz + GH[4 + og][r] + bhz);
            float ng = tanhf(GI[8 + og][r] + bin + rr * (GH[8 + og][r] + bhn));
            float hold = s[(size_t)node * 64 + o];
            float hnew = (1.0f - zz) * ng + zz * hold;
            s[(size_t)node * 64 + o] = hnew;
            s16[(size_t)node * 64 + o] = (_Float16)hnew;
        }
    }
}

// Fused Set2Set iteration: LSTM cell + attention pooling, one block(256) per graph.
// batch is sorted -> each graph's nodes are the contiguous range [gstart[g], gstart[g+1]).
__global__ void k_s2s(float* __restrict__ q_star, float* __restrict__ hh,
                      float* __restrict__ cc, const float* __restrict__ LiT,
                      const float* __restrict__ LhT, const float* __restrict__ bi,
                      const float* __restrict__ bh, const float* __restrict__ s,
                      const int* __restrict__ gstart, float* __restrict__ e_v) {
    __shared__ float qs[128], hv[64], g[256], qn[64];
    int b = blockIdx.x, t = threadIdx.x;
    if (t < 128) qs[t] = q_star[b * 128 + t];
    else if (t < 192) hv[t - 128] = hh[b * 64 + t - 128];
    __syncthreads();
    float acc = bi[t] + bh[t];
    for (int k = 0; k < 128; k++) acc += qs[k] * LiT[k * 256 + t];
    for (int k = 0; k < 64; k++) acc += hv[k] * LhT[k * 256 + t];
    g[t] = acc;
    __syncthreads();
    if (t < 64) {
        float c_new = sigf(g[64 + t]) * cc[b * 64 + t] + sigf(g[t]) * tanhf(g[128 + t]);
        cc[b * 64 + t] = c_new;
        float hq = sigf(g[192 + t]) * tanhf(c_new);
        hh[b * 64 + t] = hq;
        qn[t] = hq;
        q_star[b * 128 + t] = hq;
    }
    __syncthreads();
    if (t >= 64) return;                 // wave 0 does the pooling
    int o = t;
    int n0 = gstart[b], n1 = gstart[b + 1];
    float q = qn[o];
    float mx = -3.4e38f;
    for (int n = n0; n < n1; n++) {
        float v = s[(size_t)n * 64 + o] * q;
#pragma unroll
        for (int off = 32; off; off >>= 1) v += __shfl_xor(v, off, 64);
        if (o == 0) e_v[n] = v;
        mx = fmaxf(mx, v);
    }
    float asum = 0.0f, rp = 0.0f;
    for (int n = n0; n < n1; n++) {
        float a = __expf(e_v[n] - mx);
        asum += a;
        rp += a * s[(size_t)n * 64 + o];
    }
    q_star[b * 128 + 64 + o] = rp / (asum + 1e-16f);
}

// y[b] = relu(q_star @ lin1 + b1) @ lin2 + b2 ; one wave per graph
__global__ void k_final(const float* __restrict__ q_star, const float* __restrict__ w1,
                        const float* __restrict__ b1, const float* __restrict__ w2,
                        const float* __restrict__ b2, float* __restrict__ y) {
    __shared__ float qs[128];
    int b = blockIdx.x, t = threadIdx.x;  // 64 threads
    qs[t] = q_star[b * 128 + t];
    qs[64 + t] = q_star[b * 128 + 64 + t];
    __syncthreads();
    float acc = b1[t];
    for (int k = 0; k < 128; k++) acc += qs[k] * w1[k * 64 + t];
    float hid = fmaxf(acc, 0.0f) * w2[t];
#pragma unroll
    for (int off = 32; off; off >>= 1) hid += __shfl_down(hid, off, 64);
    if (t == 0) y[b] = hid + b2[0];
}

static inline void zero_f(float* p, size_t nfloats, hipStream_t stream) {
    int n4 = (int)(nfloats / 4);
    k_zero4<<<(n4 + 255) / 256, 256, 0, stream>>>((float4*)p, n4);
}

extern "C" void kernel_launch(void* const* d_in, const int* in_sizes, int n_in,
                              void* d_out, int out_size, void* d_ws, size_t ws_size,
                              hipStream_t stream) {
    const float* x       = (const float*)d_in[0];
    const float* z       = (const float*)d_in[1];
    const float* ea      = (const float*)d_in[2];
    const float* lin0_w  = (const float*)d_in[3];
    const float* lin0_b  = (const float*)d_in[4];
    const float* emlp_w1 = (const float*)d_in[5];
    const float* emlp_b1 = (const float*)d_in[6];
    const float* emlp_w2 = (const float*)d_in[7];
    const float* emlp_b2 = (const float*)d_in[8];
    const float* conv_r  = (const float*)d_in[9];
    const float* conv_b  = (const float*)d_in[10];
    const float* gru_wi  = (const float*)d_in[11];
    const float* gru_wh  = (const float*)d_in[12];
    const float* gru_bi  = (const float*)d_in[13];
    const float* gru_bh  = (const float*)d_in[14];
    const float* lstm_wi = (const float*)d_in[15];
    const float* lstm_wh = (const float*)d_in[16];
    const float* lstm_bi = (const float*)d_in[17];
    const float* lstm_bh = (const float*)d_in[18];
    const float* lin1_w  = (const float*)d_in[19];
    const float* lin1_b  = (const float*)d_in[20];
    const float* lin2_w  = (const float*)d_in[21];
    const float* lin2_b  = (const float*)d_in[22];
    const int* eidx      = (const int*)d_in[23];
    const int* batch     = (const int*)d_in[24];
    const int* srcI = eidx;
    const int* dstI = eidx + NE;
    float* y = (float*)d_out;

    char* w = (char*)d_ws;
    size_t off = 0;
    auto alloc = [&](size_t bytes) -> void* {
        void* p = w + off;
        off += (bytes + 255) & ~(size_t)255;
        return p;
    };
    float* s      = (float*)alloc((size_t)NN * 64 * 4);
    float* aggr   = (float*)alloc((size_t)NN * 64 * 4);
    float* deg    = (float*)alloc((size_t)NN * 4);
    float* e_v    = (float*)alloc((size_t)NN * 4);
    // contiguous zero region: q_star | hh | cc (all 256-multiples)
    float* q_star = (float*)alloc((size_t)NG * 128 * 4);
    float* hh     = (float*)alloc((size_t)NG * 64 * 4);
    float* cc     = (float*)alloc((size_t)NG * 64 * 4);
    float* LiT    = (float*)alloc(256 * 128 * 4);
    float* LhT    = (float*)alloc(256 * 64 * 4);
    int*   gstart = (int*)alloc((size_t)(NG + 1) * 4);
    _Float16* s16 = (_Float16*)alloc((size_t)NN * 64 * 2);
    _Float16* hidT= (_Float16*)alloc((size_t)132 * EPAD * 2);
    _Float16* Bp  = (_Float16*)alloc((size_t)KCH * 4 * 64 * 8 * 2);
    _Float16* Bw  = (_Float16*)alloc((size_t)56 * 64 * 8 * 2);
    (void)ws_size;  // ~64 MB total, well under proven capacity

    // weight prep
    k_transpose<<<(256 * 128 + 255) / 256, 256, 0, stream>>>(LiT, lstm_wi, 256, 128);
    k_transpose<<<(256 * 64 + 255) / 256, 256, 0, stream>>>(LhT, lstm_wh, 256, 64);
    k_prep_W<<<14, 256, 0, stream>>>(conv_r, gru_wi, gru_wh, Bw);

    // node embedding, degree, graph ranges, edge-MLP layer 1 (-> hidT f16), B prep
    k_lin0<<<NN * 64 / 256, 256, 0, stream>>>(x, z, lin0_w, lin0_b, s);
    k_s16<<<NN * 16 / 256, 256, 0, stream>>>(s, s16);
    zero_f(deg, NN, stream);
    k_deg<<<(NE + 255) / 256, 256, 0, stream>>>(dstI, deg);
    k_gstart<<<(NN + 256) / 256, 256, 0, stream>>>(batch, gstart);
    k_emlp_t<<<EPAD / 64, 256, 0, stream>>>(ea, emlp_w1, emlp_b1, hidT);
    k_prep_B<<<KCH * 4 * 64 / 256, 256, 0, stream>>>(emlp_w2, emlp_b2, Bp);

    // 5 message-passing + GRU steps
    for (int step = 0; step < 5; step++) {
        zero_f(aggr, (size_t)NN * 64, stream);
        k_fused<<<EPAD / 128, 128, 0, stream>>>(s16, hidT, Bp, srcI, dstI, aggr);
        k_combine2<<<(NN + 63) / 64, 256, 0, stream>>>(s, s16, aggr, deg, Bw,
                                                       conv_b, gru_bi, gru_bh);
    }

    // Set2Set: 5 fused LSTM+pool iterations
    zero_f(q_star, (size_t)NG * 128 + NG * 64 + NG * 64, stream);
    for (int it = 0; it < 5; it++) {
        k_s2s<<<NG, 256, 0, stream>>>(q_star, hh, cc, LiT, LhT, lstm_bi, lstm_bh,
                                      s, gstart, e_v);
    }
    k_final<<<NG, 64, 0, stream>>>(q_star, lin1_w, lin1_b, lin2_w, lin2_b, y);
}